// Round 1
// baseline (12418.340 us; speedup 1.0000x reference)
//
#include <hip/hip_runtime.h>
#include <hip/hip_bf16.h>
#include <stdint.h>

typedef unsigned short u16;
typedef float f32x4 __attribute__((ext_vector_type(4)));
typedef short s16x8 __attribute__((ext_vector_type(8)));

#define T_STEPS 512
#define NBATCH 64
#define NHID 512
#define NCOLS 2048   // 4*H
#define KIN 1024     // D+H

__device__ __forceinline__ u16 f2bf(float f) {
  uint32_t u = __builtin_bit_cast(uint32_t, f);
  u += 0x7FFFu + ((u >> 16) & 1u);
  return (u16)(u >> 16);
}
__device__ __forceinline__ float bf2f(u16 u) {
  uint32_t v = ((uint32_t)u) << 16;
  return __builtin_bit_cast(float, v);
}
__device__ __forceinline__ void gload_lds16(const void* g, void* l) {
  __builtin_amdgcn_global_load_lds(
      (const __attribute__((address_space(1))) unsigned int*)g,
      (__attribute__((address_space(3))) unsigned int*)l, 16, 0, 0);
}

// ---------------- Kernel 1: weight-norm -> Wx, Wh (bf16) ----------------
// v: [4,512,1024] f32, g: [2048] f32. Row n = gate*512+h, length 1024.
// Wx[n][k]=W[n][k] (k<512), Wh[n][k]=W[n][512+k].
__global__ void k_prep_w(const float* __restrict__ v, const float* __restrict__ g,
                         u16* __restrict__ Wx, u16* __restrict__ Wh) {
  const int row = blockIdx.x * 4 + (threadIdx.x >> 6);
  const int lane = threadIdx.x & 63;
  const float* vr = v + (size_t)row * KIN;
  float ss = 0.f;
#pragma unroll
  for (int c = 0; c < 4; ++c) {
    float4 q = *reinterpret_cast<const float4*>(vr + lane * 16 + c * 4);
    ss += q.x * q.x + q.y * q.y + q.z * q.z + q.w * q.w;
  }
#pragma unroll
  for (int off = 1; off < 64; off <<= 1) ss += __shfl_xor(ss, off);
  const float scale = g[row] / sqrtf(ss);

  s16x8 o;
  const float* src = vr + lane * 8;
#pragma unroll
  for (int i = 0; i < 8; ++i) o[i] = (short)f2bf(src[i] * scale);
  *reinterpret_cast<s16x8*>(Wx + (size_t)row * 512 + lane * 8) = o;
  const float* src2 = vr + 512 + lane * 8;
#pragma unroll
  for (int i = 0; i < 8; ++i) o[i] = (short)f2bf(src2[i] * scale);
  *reinterpret_cast<s16x8*>(Wh + (size_t)row * 512 + lane * 8) = o;
}

// ---------------- Kernel 1b: x f32 -> bf16 ----------------
__global__ void k_cvt_x(const float* __restrict__ x, u16* __restrict__ xb) {
  const size_t i = (size_t)blockIdx.x * blockDim.x + threadIdx.x;  // 0..2097151
  float4 a = *reinterpret_cast<const float4*>(x + i * 8);
  float4 b = *reinterpret_cast<const float4*>(x + i * 8 + 4);
  s16x8 o;
  o[0] = (short)f2bf(a.x); o[1] = (short)f2bf(a.y);
  o[2] = (short)f2bf(a.z); o[3] = (short)f2bf(a.w);
  o[4] = (short)f2bf(b.x); o[5] = (short)f2bf(b.y);
  o[6] = (short)f2bf(b.z); o[7] = (short)f2bf(b.w);
  *reinterpret_cast<s16x8*>(xb + i * 8) = o;
}

// ---------------- Kernel 2: xz = x @ Wx^T + b (bf16 out) ----------------
// A: x_bf16 [32768][512], B: Wx [2048][512] (bt layout), C: xz [32768][2048].
// 128x128 tile, BK=64, 256 threads, 4 waves each 64x64.
__global__ __launch_bounds__(256) void k_gemm_xz(
    const u16* __restrict__ A, const u16* __restrict__ B,
    const float* __restrict__ bias, u16* __restrict__ C) {
  __shared__ u16 As[128 * 64];
  __shared__ u16 Bs[128 * 64];
  const int tid = threadIdx.x;
  const int w = tid >> 6, l = tid & 63;
  const int l15 = l & 15, lhi = l >> 4;
  const int m0 = blockIdx.x * 128, n0 = blockIdx.y * 128;
  const int wm = (w & 1) * 64, wn = (w >> 1) * 64;
  f32x4 acc[4][4];
#pragma unroll
  for (int i = 0; i < 4; ++i)
#pragma unroll
    for (int j = 0; j < 4; ++j) acc[i][j] = (f32x4){0.f, 0.f, 0.f, 0.f};

  for (int kk = 0; kk < 8; ++kk) {
    const int kt = kk * 64;
#pragma unroll
    for (int is = 0; is < 4; ++is) {
      const int p = is * 4096 + tid * 16;  // byte offset in 16KB tile
      const int row = p >> 7, cb = p & 127;
      gload_lds16((const char*)A + (size_t)(m0 + row) * 1024 + kt * 2 + cb,
                  (char*)As + p);
      gload_lds16((const char*)B + (size_t)(n0 + row) * 1024 + kt * 2 + cb,
                  (char*)Bs + p);
    }
    __syncthreads();
#pragma unroll
    for (int ks = 0; ks < 2; ++ks) {
      s16x8 af[4], bf[4];
#pragma unroll
      for (int mt = 0; mt < 4; ++mt)
        af[mt] = *reinterpret_cast<const s16x8*>(
            (const char*)As + (wm + mt * 16 + l15) * 128 + ks * 64 + lhi * 16);
#pragma unroll
      for (int nt = 0; nt < 4; ++nt)
        bf[nt] = *reinterpret_cast<const s16x8*>(
            (const char*)Bs + (wn + nt * 16 + l15) * 128 + ks * 64 + lhi * 16);
#pragma unroll
      for (int mt = 0; mt < 4; ++mt)
#pragma unroll
        for (int nt = 0; nt < 4; ++nt)
          acc[mt][nt] = __builtin_amdgcn_mfma_f32_16x16x32_bf16(
              af[mt], bf[nt], acc[mt][nt], 0, 0, 0);
    }
    __syncthreads();
  }
#pragma unroll
  for (int nt = 0; nt < 4; ++nt) {
    const int n = n0 + wn + nt * 16 + l15;
    const float bb = bias[n];
#pragma unroll
    for (int mt = 0; mt < 4; ++mt)
#pragma unroll
      for (int r = 0; r < 4; ++r) {
        const int m = m0 + wm + mt * 16 + lhi * 4 + r;
        C[(size_t)m * 2048 + n] = f2bf(acc[mt][nt][r] + bb);
      }
  }
}

// ---------------- Kernel 3: recurrent scan ----------------
// grid (32 hid-blocks, 4 batch-groups), 256 thr (4 waves = 4 gates).
// Per block: 16 hidden units, 16 batches. Wh fragments stationary in VGPRs.
// h double-buffered in global, per-group atomic barrier each step.
__global__ __launch_bounds__(256, 1) void k_rec(
    const u16* __restrict__ Wh, const u16* __restrict__ xz,
    u16* __restrict__ h_g, unsigned* __restrict__ bar,
    float* __restrict__ out) {
  const int blk = blockIdx.x;   // hid slice 0..31
  const int grp = blockIdx.y;   // batch group 0..3
  const int tid = threadIdx.x;
  const int gate = tid >> 6;    // wave = gate (f,i,u,o)
  const int l = tid & 63;
  const int l15 = l & 15, lhi = l >> 4;
  const int hid0 = blk * 16;

  __shared__ float zbuf[4][16][17];

  // stationary B fragments: Wh row = gate*512 + hid0 + l15, k = ks*32 + lhi*8
  s16x8 bfrag[16];
  {
    const u16* wr = Wh + (size_t)(gate * 512 + hid0 + l15) * 512;
#pragma unroll
    for (int ks = 0; ks < 16; ++ks)
      bfrag[ks] = *reinterpret_cast<const s16x8*>(wr + ks * 32 + lhi * 8);
  }

  const int j2 = tid & 15;   // hid within block
  const int m2 = tid >> 4;   // batch within group, 0..15
  float creg = 0.f, hlast = 0.f;
  unsigned* mybar = bar + grp * 64;  // 256B-separated counters

  for (int t = 0; t < T_STEPS; ++t) {
    // prefetch xz (independent of h): MFMA C-layout addressing
    const u16* xp = xz + (size_t)(t * 64 + grp * 16) * 2048 + gate * 512 + hid0 + l15;
    float xv[4];
#pragma unroll
    for (int r = 0; r < 4; ++r) xv[r] = bf2f(xp[(size_t)(lhi * 4 + r) * 2048]);

    // A fragments from global h (double buffer t&1)
    const u16* hr = h_g + (size_t)(t & 1) * 32768 + (size_t)(grp * 16 + l15) * 512;
    f32x4 acc = {0.f, 0.f, 0.f, 0.f};
#pragma unroll
    for (int ks = 0; ks < 16; ++ks) {
      s16x8 a = *reinterpret_cast<const s16x8*>(hr + ks * 32 + lhi * 8);
      acc = __builtin_amdgcn_mfma_f32_16x16x32_bf16(a, bfrag[ks], acc, 0, 0, 0);
    }
#pragma unroll
    for (int r = 0; r < 4; ++r) zbuf[gate][lhi * 4 + r][l15] = acc[r] + xv[r];
    __syncthreads();

    const float zf = zbuf[0][m2][j2];
    const float zi = zbuf[1][m2][j2];
    const float zu = zbuf[2][m2][j2];
    const float zo = zbuf[3][m2][j2];
    const float ff = 1.f / (1.f + __expf(-zf));
    const float ii = 1.f / (1.f + __expf(-zi));
    const float uu = 1.f - 2.f / (__expf(2.f * zu) + 1.f);
    const float oo = 1.f / (1.f + __expf(-zo));
    creg = ff * creg + ii * uu;
    const float hn = oo * (1.f - 2.f / (__expf(2.f * creg) + 1.f));
    hlast = hn;

    h_g[(size_t)((t + 1) & 1) * 32768 + (size_t)(grp * 16 + m2) * 512 + hid0 + j2] = f2bf(hn);
    out[((size_t)t * 64 + grp * 16 + m2) * 512 + hid0 + j2] = hn;

    __threadfence();       // release h stores device-wide (cross-XCD)
    __syncthreads();       // all threads' stores issued before arrival
    if (tid == 0) {
      __hip_atomic_fetch_add(mybar, 1u, __ATOMIC_RELEASE, __HIP_MEMORY_SCOPE_AGENT);
      const unsigned tgt = (unsigned)(32 * (t + 1));  // monotonic, no reset
      while (__hip_atomic_load(mybar, __ATOMIC_ACQUIRE, __HIP_MEMORY_SCOPE_AGENT) < tgt) {}
    }
    __syncthreads();
    __threadfence();       // acquire: invalidate L1 before next h reads
  }

  float* hxp = out + (size_t)T_STEPS * 64 * 512;
  float* cxp = hxp + 64 * 512;
  hxp[(size_t)(grp * 16 + m2) * 512 + hid0 + j2] = hlast;
  cxp[(size_t)(grp * 16 + m2) * 512 + hid0 + j2] = creg;
}

extern "C" void kernel_launch(void* const* d_in, const int* in_sizes, int n_in,
                              void* d_out, int out_size, void* d_ws, size_t ws_size,
                              hipStream_t stream) {
  const float* x = (const float*)d_in[0];   // [512,64,512]
  const float* v = (const float*)d_in[1];   // [4,512,1024]
  const float* g = (const float*)d_in[2];   // [4,512]
  const float* b = (const float*)d_in[3];   // [4,512]
  float* out = (float*)d_out;

  char* ws = (char*)d_ws;
  const size_t SZ_W = 2048ull * 512 * 2;        // 2 MiB each
  u16* Wx = (u16*)(ws);
  u16* Wh = (u16*)(ws + SZ_W);
  u16* xb = (u16*)(ws + 2 * SZ_W);                               // 32 MiB
  u16* xz = (u16*)(ws + 2 * SZ_W + 32768ull * 512 * 2);          // 128 MiB
  char* hb = ws + 2 * SZ_W + 32768ull * 512 * 2 + 32768ull * 2048 * 2;
  u16* h_g = (u16*)hb;               // 2 x [64][512] bf16 = 131072 B
  unsigned* bar = (unsigned*)(hb + 131072);  // 4 counters, 256B apart

  hipMemsetAsync(hb, 0, 131072 + 1024, stream);
  k_prep_w<<<512, 256, 0, stream>>>(v, g, Wx, Wh);
  k_cvt_x<<<8192, 256, 0, stream>>>(x, xb);
  k_gemm_xz<<<dim3(256, 16), 256, 0, stream>>>(xb, Wx, b, xz);
  k_rec<<<dim3(32, 4), 256, 0, stream>>>(Wh, xz, h_g, bar, out);
}

// Round 3
// 2134.061 us; speedup vs baseline: 5.8191x; 5.8191x over previous
//
#include <hip/hip_runtime.h>
#include <hip/hip_bf16.h>
#include <stdint.h>

typedef unsigned short u16;
typedef unsigned int u32;
typedef unsigned long long u64;
typedef float f32x4 __attribute__((ext_vector_type(4)));
typedef short s16x8 __attribute__((ext_vector_type(8)));

#define T_STEPS 512
#define NBATCH 64
#define NHID 512
#define NCOLS 2048   // 4*H
#define KIN 1024     // D+H

__device__ __forceinline__ u16 f2bf(float f) {
  uint32_t u = __builtin_bit_cast(uint32_t, f);
  u += 0x7FFFu + ((u >> 16) & 1u);
  return (u16)(u >> 16);
}
__device__ __forceinline__ float bf2f(u16 u) {
  uint32_t v = ((uint32_t)u) << 16;
  return __builtin_bit_cast(float, v);
}
__device__ __forceinline__ void gload_lds16(const void* g, void* l) {
  __builtin_amdgcn_global_load_lds(
      (const __attribute__((address_space(1))) unsigned int*)g,
      (__attribute__((address_space(3))) unsigned int*)l, 16, 0, 0);
}

// ---------------- Kernel 1: weight-norm -> Wx, Wh (bf16) ----------------
__global__ void k_prep_w(const float* __restrict__ v, const float* __restrict__ g,
                         u16* __restrict__ Wx, u16* __restrict__ Wh) {
  const int row = blockIdx.x * 4 + (threadIdx.x >> 6);
  const int lane = threadIdx.x & 63;
  const float* vr = v + (size_t)row * KIN;
  float ss = 0.f;
#pragma unroll
  for (int c = 0; c < 4; ++c) {
    float4 q = *reinterpret_cast<const float4*>(vr + lane * 16 + c * 4);
    ss += q.x * q.x + q.y * q.y + q.z * q.z + q.w * q.w;
  }
#pragma unroll
  for (int off = 1; off < 64; off <<= 1) ss += __shfl_xor(ss, off);
  const float scale = g[row] / sqrtf(ss);

  s16x8 o;
  const float* src = vr + lane * 8;
#pragma unroll
  for (int i = 0; i < 8; ++i) o[i] = (short)f2bf(src[i] * scale);
  *reinterpret_cast<s16x8*>(Wx + (size_t)row * 512 + lane * 8) = o;
  const float* src2 = vr + 512 + lane * 8;
#pragma unroll
  for (int i = 0; i < 8; ++i) o[i] = (short)f2bf(src2[i] * scale);
  *reinterpret_cast<s16x8*>(Wh + (size_t)row * 512 + lane * 8) = o;
}

// ---------------- Kernel 1b: x f32 -> bf16 ----------------
__global__ void k_cvt_x(const float* __restrict__ x, u16* __restrict__ xb) {
  const size_t i = (size_t)blockIdx.x * blockDim.x + threadIdx.x;
  float4 a = *reinterpret_cast<const float4*>(x + i * 8);
  float4 b = *reinterpret_cast<const float4*>(x + i * 8 + 4);
  s16x8 o;
  o[0] = (short)f2bf(a.x); o[1] = (short)f2bf(a.y);
  o[2] = (short)f2bf(a.z); o[3] = (short)f2bf(a.w);
  o[4] = (short)f2bf(b.x); o[5] = (short)f2bf(b.y);
  o[6] = (short)f2bf(b.z); o[7] = (short)f2bf(b.w);
  *reinterpret_cast<s16x8*>(xb + i * 8) = o;
}

// ---------------- Kernel 2: xz = x @ Wx^T + b (bf16 out) ----------------
__global__ __launch_bounds__(256) void k_gemm_xz(
    const u16* __restrict__ A, const u16* __restrict__ B,
    const float* __restrict__ bias, u16* __restrict__ C) {
  __shared__ u16 As[128 * 64];
  __shared__ u16 Bs[128 * 64];
  const int tid = threadIdx.x;
  const int w = tid >> 6, l = tid & 63;
  const int l15 = l & 15, lhi = l >> 4;
  const int m0 = blockIdx.x * 128, n0 = blockIdx.y * 128;
  const int wm = (w & 1) * 64, wn = (w >> 1) * 64;
  f32x4 acc[4][4];
#pragma unroll
  for (int i = 0; i < 4; ++i)
#pragma unroll
    for (int j = 0; j < 4; ++j) acc[i][j] = (f32x4){0.f, 0.f, 0.f, 0.f};

  for (int kk = 0; kk < 8; ++kk) {
    const int kt = kk * 64;
#pragma unroll
    for (int is = 0; is < 4; ++is) {
      const int p = is * 4096 + tid * 16;
      const int row = p >> 7, cb = p & 127;
      gload_lds16((const char*)A + (size_t)(m0 + row) * 1024 + kt * 2 + cb,
                  (char*)As + p);
      gload_lds16((const char*)B + (size_t)(n0 + row) * 1024 + kt * 2 + cb,
                  (char*)Bs + p);
    }
    __syncthreads();
#pragma unroll
    for (int ks = 0; ks < 2; ++ks) {
      s16x8 af[4], bf[4];
#pragma unroll
      for (int mt = 0; mt < 4; ++mt)
        af[mt] = *reinterpret_cast<const s16x8*>(
            (const char*)As + (wm + mt * 16 + l15) * 128 + ks * 64 + lhi * 16);
#pragma unroll
      for (int nt = 0; nt < 4; ++nt)
        bf[nt] = *reinterpret_cast<const s16x8*>(
            (const char*)Bs + (wn + nt * 16 + l15) * 128 + ks * 64 + lhi * 16);
#pragma unroll
      for (int mt = 0; mt < 4; ++mt)
#pragma unroll
        for (int nt = 0; nt < 4; ++nt)
          acc[mt][nt] = __builtin_amdgcn_mfma_f32_16x16x32_bf16(
              af[mt], bf[nt], acc[mt][nt], 0, 0, 0);
    }
    __syncthreads();
  }
#pragma unroll
  for (int nt = 0; nt < 4; ++nt) {
    const int n = n0 + wn + nt * 16 + l15;
    const float bb = bias[n];
#pragma unroll
    for (int mt = 0; mt < 4; ++mt)
#pragma unroll
      for (int r = 0; r < 4; ++r) {
        const int m = m0 + wm + mt * 16 + lhi * 4 + r;
        C[(size_t)m * 2048 + n] = f2bf(acc[mt][nt][r] + bb);
      }
  }
}

// ---------------- Kernel 3: recurrent scan ----------------
// grid (32 hid-blocks, 4 batch-groups), 256 thr (4 waves = 4 gates).
// Cross-block h + barrier via RELAXED agent-scope (sc1) ops only — no
// threadfence => no buffer_wbl2/buffer_inv (that was R1's 12ms disaster).
// Barrier spin uses fetch_or(0): RMWs are serviced at the coherence point
// (MALL) unconditionally, so the spin can never read a stale line. Spin is
// bounded so a logic bug degrades to wrong-results, never a dead container.
__global__ __launch_bounds__(256, 1) void k_rec(
    const u16* __restrict__ Wh, const u16* __restrict__ xz,
    u16* __restrict__ h_g, u32* __restrict__ bar,
    float* __restrict__ out) {
  const int blk = blockIdx.x;   // hid slice 0..31
  const int grp = blockIdx.y;   // batch group 0..3
  const int tid = threadIdx.x;
  const int gate = tid >> 6;    // wave = gate (f,i,u,o)
  const int l = tid & 63;
  const int l15 = l & 15, lhi = l >> 4;
  const int hid0 = blk * 16;

  __shared__ u16 hbuf[16 * 520];      // h staging, stride 520 (bank spread)
  __shared__ float zbuf[4][16][17];

  // stationary B fragments: Wh row = gate*512 + hid0 + l15, k = ks*32 + lhi*8
  s16x8 bfrag[16];
  {
    const u16* wr = Wh + (size_t)(gate * 512 + hid0 + l15) * 512;
#pragma unroll
    for (int ks = 0; ks < 16; ++ks)
      bfrag[ks] = *reinterpret_cast<const s16x8*>(wr + ks * 32 + lhi * 8);
  }

  const int j2 = tid & 15;   // hid within block
  const int m2 = tid >> 4;   // batch within group, 0..15
  float creg = 0.f, hlast = 0.f;
  u32* mybar = bar + grp * 64;  // 256B-separated counters

  for (int t = 0; t < T_STEPS; ++t) {
    // ---- stage h(t) (group slice, 16KB) global->LDS via sc1 atomic loads ----
    u64* hg = (u64*)h_g + (size_t)(t & 1) * 8192;  // buffer = 64*512 u16 = 8192 u64
#pragma unroll
    for (int j = 0; j < 8; ++j) {
      const int q = tid + 256 * j;          // 0..2047 (16 rows * 128 u64)
      const int row = q >> 7, cu = q & 127;
      u64 vq = __hip_atomic_load(hg + (size_t)(grp * 16 + row) * 128 + cu,
                                 __ATOMIC_RELAXED, __HIP_MEMORY_SCOPE_AGENT);
      *reinterpret_cast<u64*>(hbuf + row * 520 + cu * 4) = vq;
    }
    // ---- xz prefetch (h-independent; consumed ~1000cy later) ----
    const u16* xp = xz + (size_t)(t * 64 + grp * 16) * 2048 + gate * 512 + hid0 + l15;
    float xv[4];
#pragma unroll
    for (int r = 0; r < 4; ++r) xv[r] = bf2f(xp[(size_t)(lhi * 4 + r) * 2048]);

    __syncthreads();  // hbuf ready

    // ---- recurrent MFMA: z_h = h @ Wh^T (two chains to halve latency) ----
    f32x4 acc0 = {0.f, 0.f, 0.f, 0.f}, acc1 = {0.f, 0.f, 0.f, 0.f};
#pragma unroll
    for (int ks = 0; ks < 16; ks += 2) {
      s16x8 a0 = *reinterpret_cast<const s16x8*>(hbuf + l15 * 520 + ks * 32 + lhi * 8);
      s16x8 a1 = *reinterpret_cast<const s16x8*>(hbuf + l15 * 520 + (ks + 1) * 32 + lhi * 8);
      acc0 = __builtin_amdgcn_mfma_f32_16x16x32_bf16(a0, bfrag[ks], acc0, 0, 0, 0);
      acc1 = __builtin_amdgcn_mfma_f32_16x16x32_bf16(a1, bfrag[ks + 1], acc1, 0, 0, 0);
    }
    const f32x4 acc = acc0 + acc1;
#pragma unroll
    for (int r = 0; r < 4; ++r) zbuf[gate][lhi * 4 + r][l15] = acc[r] + xv[r];
    __syncthreads();

    // ---- gate math (thread = (batch m2, hid j2)) ----
    const float zf = zbuf[0][m2][j2];
    const float zi = zbuf[1][m2][j2];
    const float zu = zbuf[2][m2][j2];
    const float zo = zbuf[3][m2][j2];
    const float ff = 1.f / (1.f + __expf(-zf));
    const float ii = 1.f / (1.f + __expf(-zi));
    const float uu = 1.f - 2.f / (__expf(2.f * zu) + 1.f);
    const float oo = 1.f / (1.f + __expf(-zo));
    creg = ff * creg + ii * uu;
    const float hn = oo * (1.f - 2.f / (__expf(2.f * creg) + 1.f));
    hlast = hn;

    out[((size_t)t * 64 + grp * 16 + m2) * 512 + hid0 + j2] = hn;

    // ---- publish h(t+1): pack lane pairs, sc1 atomic dword stores ----
    const u32 hv = f2bf(hn);
    const u32 nb = (u32)__shfl_down((int)hv, 1);
    if ((l & 1) == 0) {
      const u32 packed = hv | (nb << 16);
      u32* dst = (u32*)h_g + (size_t)((t + 1) & 1) * 16384 +
                 (((size_t)(grp * 16 + m2) * 512 + hid0 + j2) >> 1);
      __hip_atomic_store(dst, packed, __ATOMIC_RELAXED, __HIP_MEMORY_SCOPE_AGENT);
    }

    __syncthreads();  // emits s_waitcnt vmcnt(0): sc1 stores at MALL
    if (tid == 0) {
      __hip_atomic_fetch_add(mybar, 1u, __ATOMIC_RELAXED, __HIP_MEMORY_SCOPE_AGENT);
      const u32 tgt = 32u * (u32)(t + 1);  // monotonic, zeroed per launch
      // RMW-read spin: always coherent; bounded so we can never hang the box.
      for (int it = 0; it < 60000; ++it) {
        if (__hip_atomic_fetch_or(mybar, 0u, __ATOMIC_RELAXED,
                                  __HIP_MEMORY_SCOPE_AGENT) >= tgt) break;
        __builtin_amdgcn_s_sleep(1);
      }
    }
    __syncthreads();
  }

  float* hxp = out + (size_t)T_STEPS * 64 * 512;
  float* cxp = hxp + 64 * 512;
  hxp[(size_t)(grp * 16 + m2) * 512 + hid0 + j2] = hlast;
  cxp[(size_t)(grp * 16 + m2) * 512 + hid0 + j2] = creg;
}

extern "C" void kernel_launch(void* const* d_in, const int* in_sizes, int n_in,
                              void* d_out, int out_size, void* d_ws, size_t ws_size,
                              hipStream_t stream) {
  const float* x = (const float*)d_in[0];   // [512,64,512]
  const float* v = (const float*)d_in[1];   // [4,512,1024]
  const float* g = (const float*)d_in[2];   // [4,512]
  const float* b = (const float*)d_in[3];   // [4,512]
  float* out = (float*)d_out;

  char* ws = (char*)d_ws;
  const size_t SZ_W = 2048ull * 512 * 2;        // 2 MiB each
  u16* Wx = (u16*)(ws);
  u16* Wh = (u16*)(ws + SZ_W);
  u16* xb = (u16*)(ws + 2 * SZ_W);                               // 32 MiB
  u16* xz = (u16*)(ws + 2 * SZ_W + 32768ull * 512 * 2);          // 128 MiB
  char* hb = ws + 2 * SZ_W + 32768ull * 512 * 2 + 32768ull * 2048 * 2;
  u16* h_g = (u16*)hb;               // 2 x [64][512] bf16 = 131072 B
  u32* bar = (u32*)(hb + 131072);    // 4 counters, 256B apart

  hipMemsetAsync(hb, 0, 131072 + 1024, stream);
  k_prep_w<<<512, 256, 0, stream>>>(v, g, Wx, Wh);
  k_cvt_x<<<8192, 256, 0, stream>>>(x, xb);
  k_gemm_xz<<<dim3(256, 16), 256, 0, stream>>>(xb, Wx, b, xz);
  k_rec<<<dim3(32, 4), 256, 0, stream>>>(Wh, xz, h_g, bar, out);
}

// Round 4
// 2110.322 us; speedup vs baseline: 5.8846x; 1.0112x over previous
//
#include <hip/hip_runtime.h>
#include <hip/hip_bf16.h>
#include <stdint.h>

typedef unsigned short u16;
typedef unsigned int u32;
typedef unsigned long long u64;
typedef float f32x4 __attribute__((ext_vector_type(4)));
typedef short s16x8 __attribute__((ext_vector_type(8)));

#define T_STEPS 512
#define NBATCH 64
#define NHID 512
#define NCOLS 2048   // 4*H
#define KIN 1024     // D+H

__device__ __forceinline__ u16 f2bf(float f) {
  uint32_t u = __builtin_bit_cast(uint32_t, f);
  u += 0x7FFFu + ((u >> 16) & 1u);
  return (u16)(u >> 16);
}
__device__ __forceinline__ float bf2f(u16 u) {
  uint32_t v = ((uint32_t)u) << 16;
  return __builtin_bit_cast(float, v);
}
__device__ __forceinline__ void gload_lds16(const void* g, void* l) {
  __builtin_amdgcn_global_load_lds(
      (const __attribute__((address_space(1))) unsigned int*)g,
      (__attribute__((address_space(3))) unsigned int*)l, 16, 0, 0);
}

// ---------------- Kernel 1: weight-norm -> Wx, Wh (bf16) ----------------
__global__ void k_prep_w(const float* __restrict__ v, const float* __restrict__ g,
                         u16* __restrict__ Wx, u16* __restrict__ Wh) {
  const int row = blockIdx.x * 4 + (threadIdx.x >> 6);
  const int lane = threadIdx.x & 63;
  const float* vr = v + (size_t)row * KIN;
  float ss = 0.f;
#pragma unroll
  for (int c = 0; c < 4; ++c) {
    float4 q = *reinterpret_cast<const float4*>(vr + lane * 16 + c * 4);
    ss += q.x * q.x + q.y * q.y + q.z * q.z + q.w * q.w;
  }
#pragma unroll
  for (int off = 1; off < 64; off <<= 1) ss += __shfl_xor(ss, off);
  const float scale = g[row] / sqrtf(ss);

  s16x8 o;
  const float* src = vr + lane * 8;
#pragma unroll
  for (int i = 0; i < 8; ++i) o[i] = (short)f2bf(src[i] * scale);
  *reinterpret_cast<s16x8*>(Wx + (size_t)row * 512 + lane * 8) = o;
  const float* src2 = vr + 512 + lane * 8;
#pragma unroll
  for (int i = 0; i < 8; ++i) o[i] = (short)f2bf(src2[i] * scale);
  *reinterpret_cast<s16x8*>(Wh + (size_t)row * 512 + lane * 8) = o;
}

// ---------------- Kernel 1b: x f32 -> bf16 ----------------
__global__ void k_cvt_x(const float* __restrict__ x, u16* __restrict__ xb) {
  const size_t i = (size_t)blockIdx.x * blockDim.x + threadIdx.x;
  float4 a = *reinterpret_cast<const float4*>(x + i * 8);
  float4 b = *reinterpret_cast<const float4*>(x + i * 8 + 4);
  s16x8 o;
  o[0] = (short)f2bf(a.x); o[1] = (short)f2bf(a.y);
  o[2] = (short)f2bf(a.z); o[3] = (short)f2bf(a.w);
  o[4] = (short)f2bf(b.x); o[5] = (short)f2bf(b.y);
  o[6] = (short)f2bf(b.z); o[7] = (short)f2bf(b.w);
  *reinterpret_cast<s16x8*>(xb + i * 8) = o;
}

// ---------------- Kernel 2: xz = x @ Wx^T + b (bf16 out) ----------------
__global__ __launch_bounds__(256) void k_gemm_xz(
    const u16* __restrict__ A, const u16* __restrict__ B,
    const float* __restrict__ bias, u16* __restrict__ C) {
  __shared__ u16 As[128 * 64];
  __shared__ u16 Bs[128 * 64];
  const int tid = threadIdx.x;
  const int w = tid >> 6, l = tid & 63;
  const int l15 = l & 15, lhi = l >> 4;
  const int m0 = blockIdx.x * 128, n0 = blockIdx.y * 128;
  const int wm = (w & 1) * 64, wn = (w >> 1) * 64;
  f32x4 acc[4][4];
#pragma unroll
  for (int i = 0; i < 4; ++i)
#pragma unroll
    for (int j = 0; j < 4; ++j) acc[i][j] = (f32x4){0.f, 0.f, 0.f, 0.f};

  for (int kk = 0; kk < 8; ++kk) {
    const int kt = kk * 64;
#pragma unroll
    for (int is = 0; is < 4; ++is) {
      const int p = is * 4096 + tid * 16;
      const int row = p >> 7, cb = p & 127;
      gload_lds16((const char*)A + (size_t)(m0 + row) * 1024 + kt * 2 + cb,
                  (char*)As + p);
      gload_lds16((const char*)B + (size_t)(n0 + row) * 1024 + kt * 2 + cb,
                  (char*)Bs + p);
    }
    __syncthreads();
#pragma unroll
    for (int ks = 0; ks < 2; ++ks) {
      s16x8 af[4], bf[4];
#pragma unroll
      for (int mt = 0; mt < 4; ++mt)
        af[mt] = *reinterpret_cast<const s16x8*>(
            (const char*)As + (wm + mt * 16 + l15) * 128 + ks * 64 + lhi * 16);
#pragma unroll
      for (int nt = 0; nt < 4; ++nt)
        bf[nt] = *reinterpret_cast<const s16x8*>(
            (const char*)Bs + (wn + nt * 16 + l15) * 128 + ks * 64 + lhi * 16);
#pragma unroll
      for (int mt = 0; mt < 4; ++mt)
#pragma unroll
        for (int nt = 0; nt < 4; ++nt)
          acc[mt][nt] = __builtin_amdgcn_mfma_f32_16x16x32_bf16(
              af[mt], bf[nt], acc[mt][nt], 0, 0, 0);
    }
    __syncthreads();
  }
#pragma unroll
  for (int nt = 0; nt < 4; ++nt) {
    const int n = n0 + wn + nt * 16 + l15;
    const float bb = bias[n];
#pragma unroll
    for (int mt = 0; mt < 4; ++mt)
#pragma unroll
      for (int r = 0; r < 4; ++r) {
        const int m = m0 + wm + mt * 16 + lhi * 4 + r;
        C[(size_t)m * 2048 + n] = f2bf(acc[mt][nt][r] + bb);
      }
  }
}

// ---------------- Kernel 3: recurrent scan ----------------
// grid (32 hid-blocks, 4 batch-groups), 256 thr (4 waves = 4 gates).
// Cross-block h via RELAXED agent-scope (sc1) ops. Barrier = per-producer
// monotonic flags + read-only polling: NO RMW in steady state (R3's fetch_or
// spin serialized 32 contenders on one MALL line — that was the 8900cy/step).
// Release = __syncthreads' vmcnt(0) drain before the flag store.
__global__ __launch_bounds__(256, 1) void k_rec(
    const u16* __restrict__ Wh, const u16* __restrict__ xz,
    u16* __restrict__ h_g, u32* __restrict__ bar,
    float* __restrict__ out) {
  const int blk = blockIdx.x;   // hid slice 0..31
  const int grp = blockIdx.y;   // batch group 0..3
  const int tid = threadIdx.x;
  const int gate = tid >> 6;    // wave = gate (f,i,u,o)
  const int l = tid & 63;
  const int l15 = l & 15, lhi = l >> 4;
  const int hid0 = blk * 16;

  __shared__ u16 hbuf[16 * 520];      // h staging, stride 520 (bank spread)
  __shared__ float zbuf[4][16][17];

  // stationary B fragments: Wh row = gate*512 + hid0 + l15, k = ks*32 + lhi*8
  s16x8 bfrag[16];
  {
    const u16* wr = Wh + (size_t)(gate * 512 + hid0 + l15) * 512;
#pragma unroll
    for (int ks = 0; ks < 16; ++ks)
      bfrag[ks] = *reinterpret_cast<const s16x8*>(wr + ks * 32 + lhi * 8);
  }

  const int j2 = tid & 15;   // hid within block
  const int m2 = tid >> 4;   // batch within group, 0..15
  float creg = 0.f, hlast = 0.f;
  u32* myflags = bar + grp * 32;     // 32 producer flags for this group

  for (int t = 0; t < T_STEPS; ++t) {
    // ---- wait for h(t): every wave polls all 32 flags (read-only) ----
    if (t > 0) {
      const u32 tgt = (u32)t;
      bool ready = false;
      for (int it = 0; it < 50000 && !ready; ++it) {
        u32 fv = __hip_atomic_load(myflags + (l & 31), __ATOMIC_RELAXED,
                                   __HIP_MEMORY_SCOPE_AGENT);
        ready = __all(fv >= tgt);
      }
    }

    // ---- stage h(t) (group slice, 16KB) global->LDS via sc1 atomic loads ----
    u64* hg = (u64*)h_g + (size_t)(t & 1) * 8192;  // buffer = 64*512 u16 = 8192 u64
#pragma unroll
    for (int j = 0; j < 8; ++j) {
      const int q = tid + 256 * j;          // 0..2047 (16 rows * 128 u64)
      const int row = q >> 7, cu = q & 127;
      u64 vq = __hip_atomic_load(hg + (size_t)(grp * 16 + row) * 128 + cu,
                                 __ATOMIC_RELAXED, __HIP_MEMORY_SCOPE_AGENT);
      *reinterpret_cast<u64*>(hbuf + row * 520 + cu * 4) = vq;
    }
    // ---- xz prefetch (h-independent) ----
    const u16* xp = xz + (size_t)(t * 64 + grp * 16) * 2048 + gate * 512 + hid0 + l15;
    float xv[4];
#pragma unroll
    for (int r = 0; r < 4; ++r) xv[r] = bf2f(xp[(size_t)(lhi * 4 + r) * 2048]);

    __syncthreads();  // hbuf ready

    // ---- recurrent MFMA: z_h = h @ Wh^T (two chains) ----
    f32x4 acc0 = {0.f, 0.f, 0.f, 0.f}, acc1 = {0.f, 0.f, 0.f, 0.f};
#pragma unroll
    for (int ks = 0; ks < 16; ks += 2) {
      s16x8 a0 = *reinterpret_cast<const s16x8*>(hbuf + l15 * 520 + ks * 32 + lhi * 8);
      s16x8 a1 = *reinterpret_cast<const s16x8*>(hbuf + l15 * 520 + (ks + 1) * 32 + lhi * 8);
      acc0 = __builtin_amdgcn_mfma_f32_16x16x32_bf16(a0, bfrag[ks], acc0, 0, 0, 0);
      acc1 = __builtin_amdgcn_mfma_f32_16x16x32_bf16(a1, bfrag[ks + 1], acc1, 0, 0, 0);
    }
    const f32x4 acc = acc0 + acc1;
#pragma unroll
    for (int r = 0; r < 4; ++r) zbuf[gate][lhi * 4 + r][l15] = acc[r] + xv[r];
    __syncthreads();

    // ---- gate math (thread = (batch m2, hid j2)) ----
    const float zf = zbuf[0][m2][j2];
    const float zi = zbuf[1][m2][j2];
    const float zu = zbuf[2][m2][j2];
    const float zo = zbuf[3][m2][j2];
    const float ff = 1.f / (1.f + __expf(-zf));
    const float ii = 1.f / (1.f + __expf(-zi));
    const float uu = 1.f - 2.f / (__expf(2.f * zu) + 1.f);
    const float oo = 1.f / (1.f + __expf(-zo));
    creg = ff * creg + ii * uu;
    const float hn = oo * (1.f - 2.f / (__expf(2.f * creg) + 1.f));
    hlast = hn;

    // ---- publish h(t+1): pack lane pairs, sc1 atomic dword stores ----
    const u32 hv = f2bf(hn);
    const u32 nb = (u32)__shfl_down((int)hv, 1);
    if ((l & 1) == 0) {
      const u32 packed = hv | (nb << 16);
      u32* dst = (u32*)h_g + (size_t)((t + 1) & 1) * 16384 +
                 (((size_t)(grp * 16 + m2) * 512 + hid0 + j2) >> 1);
      __hip_atomic_store(dst, packed, __ATOMIC_RELAXED, __HIP_MEMORY_SCOPE_AGENT);
    }

    __syncthreads();  // every wave drains vmcnt(0): all h stores at MALL
    if (tid == 0)     // flag release: fire-and-forget, no RMW
      __hip_atomic_store(myflags + blk, (u32)(t + 1), __ATOMIC_RELAXED,
                         __HIP_MEMORY_SCOPE_AGENT);
    // out-store AFTER the flag: overlaps the next poll instead of the drain
    out[((size_t)t * 64 + grp * 16 + m2) * 512 + hid0 + j2] = hn;
  }

  float* hxp = out + (size_t)T_STEPS * 64 * 512;
  float* cxp = hxp + 64 * 512;
  hxp[(size_t)(grp * 16 + m2) * 512 + hid0 + j2] = hlast;
  cxp[(size_t)(grp * 16 + m2) * 512 + hid0 + j2] = creg;
}

extern "C" void kernel_launch(void* const* d_in, const int* in_sizes, int n_in,
                              void* d_out, int out_size, void* d_ws, size_t ws_size,
                              hipStream_t stream) {
  const float* x = (const float*)d_in[0];   // [512,64,512]
  const float* v = (const float*)d_in[1];   // [4,512,1024]
  const float* g = (const float*)d_in[2];   // [4,512]
  const float* b = (const float*)d_in[3];   // [4,512]
  float* out = (float*)d_out;

  char* ws = (char*)d_ws;
  const size_t SZ_W = 2048ull * 512 * 2;        // 2 MiB each
  u16* Wx = (u16*)(ws);
  u16* Wh = (u16*)(ws + SZ_W);
  u16* xb = (u16*)(ws + 2 * SZ_W);                               // 32 MiB
  u16* xz = (u16*)(ws + 2 * SZ_W + 32768ull * 512 * 2);          // 128 MiB
  char* hb = ws + 2 * SZ_W + 32768ull * 512 * 2 + 32768ull * 2048 * 2;
  u16* h_g = (u16*)hb;               // 2 x [64][512] bf16 = 131072 B
  u32* bar = (u32*)(hb + 131072);    // flags[4][32] u32, zeroed per launch

  hipMemsetAsync(hb, 0, 131072 + 1024, stream);
  k_prep_w<<<512, 256, 0, stream>>>(v, g, Wx, Wh);
  k_cvt_x<<<8192, 256, 0, stream>>>(x, xb);
  k_gemm_xz<<<dim3(256, 16), 256, 0, stream>>>(xb, Wx, b, xz);
  k_rec<<<dim3(32, 4), 256, 0, stream>>>(Wh, xz, h_g, bar, out);
}